// Round 1
// 494.761 us; speedup vs baseline: 1.1185x; 1.1185x over previous
//
#include <hip/hip_runtime.h>
#include <math.h>

#define NPG  100
#define NGR  2048
#define EPG  800
#define HID  64
#define LATD 193
#define KTOP 30
#define NTHR 1024
#define NWV  16
#define ROWS 7      // ceil(100/16)
#define MAXD 32

// ---------------- LDS layout (byte offsets), 64912 B ------------------------
// <= 64 KiB so TWO 16-wave workgroups co-reside per CU (the old 67856 B
// footprint clamped residency to 1 WG/CU: occupancy 45.7%, VALUBusy 45%).
#define OFF_H64    0       // double[101][64] = 51712 (row 100 = zero sentinel)
#define OFF_ADJ    51712   // ushort[100*32] = 6400 -> 58112 (BYTE offsets u*512; bits0-2 of row[0] = group count)
#define OFF_Y1ALL  58112   // float[100*16] = 6400 -> 64512
#define OFF_DINV   64512   // float[100] = 400 -> 64912 (f64 rsqrt rounded once)
#define SMEM_SZ    64912
// pre-phase-A overlays inside y1all (dead after pad/sort; y1all zeroed later):
#define OFF_ZL     OFF_Y1ALL           // int[100]
#define OFF_CNT    (OFF_Y1ALL + 400)   // int[100]
// tail overlays inside dead h64 region:
#define OFF_Y1P    0       // 960
#define OFF_Y2F    960     // 960+1408 -> 2368
#define OFF_PART   2368    // 8*128*4 = 4096 -> 6464
#define OFF_O128   6464    // 512 -> 6976
#define OFF_Y1     6976    // 16*30*4 = 1920 -> 8896
#define OFF_S4     8896    // double[101] = 808 -> 9704 (written AFTER h64 dead, reg-staged)
#define OFF_KEY64  9704    // double[100] = 800 -> 10504
#define OFF_SEL    10504   // int[32] = 128 -> 10632

// Branch-free f64 tanh (abs err ~1e-13). Divide replaced by float-seeded
// reciprocal + 2 Newton steps (rel err ~1e-28 -> <=1 ulp): saves ~10 f64 ops
// vs IEEE divide. Proven-safe error budget from r7/r9 (1e-13 poly) dominates.
__device__ __forceinline__ double ftanh64(double x) {
    const double y  = fmin(fabs(x) * 2.0, 44.0);
    const double nf = rint(y * 1.4426950408889634074);
    double r = fma(-nf, 6.93147180369123816490e-01, y);
    r = fma(-nf, 1.90821492927058770002e-10, r);
    double p = 2.7557319223985888e-07;
    p = fma(p, r, 2.7557319223985893e-06);
    p = fma(p, r, 2.4801587301587302e-05);
    p = fma(p, r, 1.9841269841269841e-04);
    p = fma(p, r, 1.3888888888888889e-03);
    p = fma(p, r, 8.3333333333333332e-03);
    p = fma(p, r, 4.1666666666666664e-02);
    p = fma(p, r, 1.6666666666666666e-01);
    p = fma(p, r, 0.5);
    p = fma(p, r, 1.0);
    p = fma(p, r, 1.0);
    const double e = p * __longlong_as_double((long long)(1023 + (int)nf) << 52);
    const double d = e + 1.0;
    double rc = (double)(1.0f / (float)d);        // f32 seed (~1.2e-7 rel)
    rc = fma(fma(-d, rc, 1.0), rc, rc);           // Newton 1 -> ~1.4e-14
    rc = fma(fma(-d, rc, 1.0), rc, rc);           // Newton 2 -> exact-ish
    const double t = fma(-2.0, rc, 1.0);
    return copysign(t, x);
}

// f64 in-place GCN layer. Matmul: 4 quarter-passes (wf[16] live) into
// persistent acc[7]. Aggregation: pure f64 adds over byte-offset adjacency
// (pre-scaled h), DEGREE-ADAPTIVE: group count gq decoded from bits 0-2 of
// the row's first entry (mask 0xFE00 strips it from the offset; same cost as
// the old 0xFFFF). Row n is wave-uniform -> uniform trip count; sentinel
// terms are exact +0.0, so sums stay bit-identical to the cnt[] version.
__device__ __forceinline__ void gcnA(
    double* __restrict__ h, const float* __restrict__ dinv,
    const unsigned short* __restrict__ adj,
    const float* __restrict__ W, const float* __restrict__ b, int lane, int wv)
{
    double acc[ROWS];
#pragma unroll
    for (int i = 0; i < ROWS; ++i) acc[i] = 0.;

#pragma unroll 1   // one quarter live at a time: wf[16] not wf[64] (r10/r11 spill fix)
    for (int quarter = 0; quarter < 4; ++quarter) {
        float wf[16];
#pragma unroll
        for (int k = 0; k < 16; ++k) wf[k] = W[(quarter*16 + k)*HID + lane];
#pragma unroll
        for (int i = 0; i < ROWS; ++i) {
            const int n = wv + NWV*i;
            if (n < NPG) {
                const double2* r2 = (const double2*)&h[n*HID + quarter*16];
                double a0=0., a1=0., a2=0., a3=0.;
#pragma unroll
                for (int k2 = 0; k2 < 4; ++k2) {
                    const double2 x01 = r2[2*k2], x23 = r2[2*k2+1];
                    a0 = fma(x01.x, (double)wf[4*k2+0], a0);
                    a1 = fma(x01.y, (double)wf[4*k2+1], a1);
                    a2 = fma(x23.x, (double)wf[4*k2+2], a2);
                    a3 = fma(x23.y, (double)wf[4*k2+3], a3);
                }
                acc[i] += (a0+a1)+(a2+a3);
            }
        }
    }
#pragma unroll
    for (int i = 0; i < ROWS; ++i) {
        const int n = wv + NWV*i;
        if (n < NPG) h[n*HID + lane] = acc[i] * (double)dinv[n];   // pre-scaled write
    }
    __syncthreads();

    const double bj = (double)b[lane];
    const char* hb = (const char*)h + lane*8;
    double agg[ROWS];
#pragma unroll
    for (int i = 0; i < ROWS; ++i) {
        const int n = wv + NWV*i;
        if (n < NPG) {
            const uint4* arow = (const uint4*)&adj[n*MAXD];
            const uint4 q0 = arow[0];
            const int gq = q0.x & 7;          // encoded group count (0..4)
            double a0, a1;
            a0  = *(const double*)(hb + (q0.x & 0xFE00));
            a1  = *(const double*)(hb + (q0.x >> 16));
            a0 += *(const double*)(hb + (q0.y & 0xFE00));
            a1 += *(const double*)(hb + (q0.y >> 16));
            a0 += *(const double*)(hb + (q0.z & 0xFE00));
            a1 += *(const double*)(hb + (q0.z >> 16));
            a0 += *(const double*)(hb + (q0.w & 0xFE00));
            a1 += *(const double*)(hb + (q0.w >> 16));
#pragma unroll 1   // serial q-loop: full flattening spilled (r5/r6 evidence)
            for (int q = 1; q < gq; ++q) {
                const uint4 qq = arow[q];
                a0 += *(const double*)(hb + (qq.x & 0xFE00));
                a1 += *(const double*)(hb + (qq.x >> 16));
                a0 += *(const double*)(hb + (qq.y & 0xFE00));
                a1 += *(const double*)(hb + (qq.y >> 16));
                a0 += *(const double*)(hb + (qq.z & 0xFE00));
                a1 += *(const double*)(hb + (qq.z >> 16));
                a0 += *(const double*)(hb + (qq.w & 0xFE00));
                a1 += *(const double*)(hb + (qq.w >> 16));
            }
            agg[i] = fma((a0+a1) + h[n*HID+lane], (double)dinv[n], bj);
        }
    }
    __syncthreads();
#pragma unroll
    for (int i = 0; i < ROWS; ++i) {
        const int n = wv + NWV*i;
        if (n < NPG) h[n*HID + lane] = ftanh64(agg[i]);
    }
    // no trailing barrier: post-agg ops touch only own rows until next matmul barrier
}

// conv1 partial dots for layer l, accumulated straight into LDS y1all.
// Quad-split: lane = ch*4+j. unroll 4 caps in-flight f64 loads (reg budget).
__device__ __forceinline__ void dot_accum(
    const double* __restrict__ h, const float* __restrict__ c1w,
    float* __restrict__ y1all, int lane, int wv, int l)
{
    const int ch = lane >> 2, j = lane & 3;
    const float* wp = &c1w[ch*LATD + l*HID + j*16];
    float wreg[16];
#pragma unroll
    for (int k = 0; k < 16; ++k) wreg[k] = wp[k];
#pragma unroll
    for (int i = 0; i < ROWS; ++i) {
        const int n = wv + NWV*i;
        if (n < NPG) {
            const double* hr = &h[n*HID + j*16];
            float s = 0.f;
#pragma unroll 4
            for (int k = 0; k < 16; ++k) s = fmaf((float)hr[k], wreg[k], s);
            s += __shfl_xor(s, 1, 64);
            s += __shfl_xor(s, 2, 64);
            if (j == 0) y1all[n*16 + ch] += s;   // unique (n,ch) owner
        }
    }
}

__global__ __launch_bounds__(NTHR, 8)   // 8 waves/SIMD = 2 blocks/CU: pin VGPR <= 64
void seal_fused(const int* __restrict__ z,
                const int* __restrict__ esrc, const int* __restrict__ edst,
                const float* __restrict__ zemb,
                const float* __restrict__ W0, const float* __restrict__ b0,
                const float* __restrict__ W1, const float* __restrict__ b1,
                const float* __restrict__ W2, const float* __restrict__ b2,
                const float* __restrict__ W3, const float* __restrict__ b3,
                const float* __restrict__ c1w, const float* __restrict__ c1b,
                const float* __restrict__ c2w, const float* __restrict__ c2b,
                const float* __restrict__ l1w, const float* __restrict__ l1b,
                const float* __restrict__ l2w, const float* __restrict__ l2b,
                float* __restrict__ out)
{
    __shared__ __align__(16) char smem[SMEM_SZ];
    double* h64    = (double*)(smem + OFF_H64);
    unsigned short* adj = (unsigned short*)(smem + OFF_ADJ);
    float*  y1all  = (float*) (smem + OFF_Y1ALL);
    float*  dinv   = (float*) (smem + OFF_DINV);
    int*    zl     = (int*)   (smem + OFF_ZL);
    int*    cnt    = (int*)   (smem + OFF_CNT);
    double* s4     = (double*)(smem + OFF_S4);
    double* key64  = (double*)(smem + OFF_KEY64);
    int*    sel    = (int*)   (smem + OFF_SEL);
    float*  y1     = (float*) (smem + OFF_Y1);
    float*  y1p    = (float*) (smem + OFF_Y1P);
    float*  y2f    = (float*) (smem + OFF_Y2F);
    float*  part   = (float*) (smem + OFF_PART);
    float*  o128   = (float*) (smem + OFF_O128);

    const int g     = blockIdx.x;
    const int t     = threadIdx.x;
    const int lane  = t & 63;
    const int wv    = t >> 6;
    const int nbase = g * NPG;
    const int ebase = g * EPG;

    // ---- stage edges in registers (single global read; one edge/thread) ----
    int e0s = 0, e0d = -1;
    if (t < EPG) { e0s = esrc[ebase+t] - nbase; e0d = edst[ebase+t] - nbase; }
    for (int i = t; i < NPG; i += NTHR) { zl[i] = z[nbase+i]; cnt[i] = 0; }
    __syncthreads();
    if (e0d >= 0) atomicAdd(&cnt[e0d], 1);
    __syncthreads();
    for (int i = t; i < NPG; i += NTHR) {
        dinv[i] = (float)(1.0 / sqrt((double)(cnt[i] + 1)));
        cnt[i] = 0;
    }
    __syncthreads();
    // ---- adjacency fill: BYTE offsets u*512 into the f64 h array ----
    if (e0d >= 0) { const int p = atomicAdd(&cnt[e0d], 1); if (p < MAXD) adj[e0d*MAXD + p] = (unsigned short)(e0s << 9); }
    __syncthreads();
    // ---- pad + sort rows (deterministic accumulation) ; embedding gather ----
    if (t < NPG) {
        const int deg = min(cnt[t], MAXD);
        unsigned short* row = &adj[t*MAXD];
        for (int j = deg; j < MAXD; ++j) row[j] = (unsigned short)(NPG << 9);  // -> zero row
        for (int a = 1; a < deg; ++a) {
            const unsigned short x = row[a];
            int bp = a - 1;
            while (bp >= 0 && row[bp] > x) { row[bp+1] = row[bp]; --bp; }
            row[bp+1] = x;
        }
        row[0] |= (unsigned short)((deg + 7) >> 3);   // encode gq; cnt[] dies here
    }
    for (int i = t; i < (NPG+1)*HID; i += NTHR) {
        const int n = i >> 6, k = i & 63;
        h64[i] = (n < NPG) ? (double)zemb[zl[n]*HID + k] : 0.0;   // row 100 = 0
    }
    __syncthreads();
    // zl/cnt overlays now dead: reclaim as y1all zeros. Ordering vs first
    // dot_accum is guaranteed by gcnA's internal barriers.
    for (int i = t; i < NPG*16; i += NTHR) y1all[i] = 0.f;

    // ====== phase A (f64): layers 0..2 with fused conv1 dot accumulation =====
    gcnA(h64, dinv, adj, W0, b0, lane, wv);
    dot_accum(h64, c1w, y1all, lane, wv, 0);
    gcnA(h64, dinv, adj, W1, b1, lane, wv);
    dot_accum(h64, c1w, y1all, lane, wv, 1);
    gcnA(h64, dinv, adj, W2, b2, lane, wv);
    dot_accum(h64, c1w, y1all, lane, wv, 2);

    // ---- s4 = (h3 @ W3) * dinv (pre-scaled), f64, own rows ----
    // Register-staged: the s4 LDS slot overlays h64, so values are held in
    // regs until the barrier proves every wave finished reading h64.
    double s4r[ROWS];
    {
        const double w3d = (double)W3[lane];
#pragma unroll
        for (int i = 0; i < ROWS; ++i) {
            const int n = wv + NWV*i;
            if (n < NPG) {
                double v = h64[n*HID + lane] * w3d;
#pragma unroll
                for (int off = 32; off; off >>= 1) v += __shfl_xor(v, off, 64);
                s4r[i] = v * (double)dinv[n];
            }
        }
    }
    __syncthreads();            // h64 fully dead -> overlay region writable
#pragma unroll
    for (int i = 0; i < ROWS; ++i) {
        const int n = wv + NWV*i;
        if (n < NPG && lane == 0) s4[n] = s4r[i];
    }
    if (t == 0) s4[NPG] = 0.0;  // sentinel for key aggregation
    __syncthreads();
    // ---- layer-3 aggregate -> f64 sort keys (degree-adaptive) ----
    if (t < NPG) {
        const char* sb = (const char*)s4;
        const uint4* arow = (const uint4*)&adj[t*MAXD];
        const uint4 q0 = arow[0];
        const int gq = q0.x & 7;
        double acc;
        {
            const double z0 = *(const double*)(sb + ((q0.x & 0xFE00) >> 6));
            const double z1 = *(const double*)(sb + ((q0.x >> 16)    >> 6));
            const double z2 = *(const double*)(sb + ((q0.y & 0xFE00) >> 6));
            const double z3 = *(const double*)(sb + ((q0.y >> 16)    >> 6));
            const double z4 = *(const double*)(sb + ((q0.z & 0xFE00) >> 6));
            const double z5 = *(const double*)(sb + ((q0.z >> 16)    >> 6));
            const double z6 = *(const double*)(sb + ((q0.w & 0xFE00) >> 6));
            const double z7 = *(const double*)(sb + ((q0.w >> 16)    >> 6));
            acc = ((z0+z1)+(z2+z3)) + ((z4+z5)+(z6+z7));
        }
#pragma unroll 1
        for (int q = 1; q < gq; ++q) {
            const uint4 qq = arow[q];
            const double z0 = *(const double*)(sb + ((qq.x & 0xFE00) >> 6));
            const double z1 = *(const double*)(sb + ((qq.x >> 16)    >> 6));
            const double z2 = *(const double*)(sb + ((qq.y & 0xFE00) >> 6));
            const double z3 = *(const double*)(sb + ((qq.y >> 16)    >> 6));
            const double z4 = *(const double*)(sb + ((qq.z & 0xFE00) >> 6));
            const double z5 = *(const double*)(sb + ((qq.z >> 16)    >> 6));
            const double z6 = *(const double*)(sb + ((qq.w & 0xFE00) >> 6));
            const double z7 = *(const double*)(sb + ((qq.w >> 16)    >> 6));
            acc += ((z0+z1)+(z2+z3)) + ((z4+z5)+(z6+z7));
        }
        key64[t] = ftanh64(fma(acc + s4[t], (double)dinv[t], (double)b3[0]));
    }
    __syncthreads();
    // ---- stable top-K rank counting on f64 keys ----
    if (t < NPG) {
        const double kv = key64[t];
        int r = 0;
        for (int m = 0; m < NPG; ++m) {
            const double km = key64[m];
            r += (km > kv) || (km == kv && m < t);
        }
        if (r < KTOP) sel[r] = t;
    }
    __syncthreads();
    // ---- y1 assembly: partial dot + bias + key-channel term ----
    if (t < 16*KTOP) {
        const int ch = t & 15, r = t >> 4;
        const int n = sel[r];
        y1[ch*KTOP + r] = y1all[n*16 + ch] + c1b[ch]
                        + (float)key64[n] * c1w[ch*LATD + 192];
    }
    __syncthreads();
    // ---- maxpool(2,2) + fused relu ----
    if (t < 16*15) {
        const int ch = t & 15, p = t >> 4;
        y1p[ch*15 + p] = fmaxf(fmaxf(y1[ch*KTOP + 2*p], y1[ch*KTOP + 2*p + 1]), 0.f);
    }
    __syncthreads();
    // ---- conv2 [32][16][5], relu (weights from L2) ----
    if (t < 32*11) {
        const int o = t & 31, p = t >> 5;
        float acc = c2b[o];
        const float* wr = &c2w[o*80];
#pragma unroll
        for (int i = 0; i < 16; ++i)
#pragma unroll
            for (int kk = 0; kk < 5; ++kk)
                acc = fmaf(wr[i*5+kk], y1p[i*15 + p + kk], acc);
        y2f[o*11 + p] = fmaxf(acc, 0.f);
    }
    __syncthreads();
    // ---- lin1: 352 -> 128 (8-way f-split), relu ----
    {
        const int j = t & 127, pid = t >> 7;      // pid 0..7
        const int f0 = pid * 44;
        float acc = 0.f;
        for (int f = f0; f < f0 + 44; ++f) acc = fmaf(y2f[f], l1w[f*128 + j], acc);
        part[pid*128 + j] = acc;
    }
    __syncthreads();
    if (t < 128) {
        float acc = l1b[t];
#pragma unroll
        for (int pid = 0; pid < 8; ++pid) acc += part[pid*128 + t];
        o128[t] = fmaxf(acc, 0.f);
    }
    __syncthreads();
    // ---- lin2: 128 -> 1 ----
    if (t < 64) {
        float acc = fmaf(o128[t], l2w[t], o128[t+64]*l2w[t+64]);
#pragma unroll
        for (int off = 32; off; off >>= 1) acc += __shfl_xor(acc, off, 64);
        if (t == 0) out[g] = acc + l2b[0];
    }
}

extern "C" void kernel_launch(void* const* d_in, const int* in_sizes, int n_in,
                              void* d_out, int out_size, void* d_ws, size_t ws_size,
                              hipStream_t stream)
{
    const int*   z    = (const int*)d_in[0];
    const int*   ei   = (const int*)d_in[1];
    const float* zemb = (const float*)d_in[3];
    const float* W0   = (const float*)d_in[4];
    const float* b0   = (const float*)d_in[5];
    const float* W1   = (const float*)d_in[6];
    const float* b1   = (const float*)d_in[7];
    const float* W2   = (const float*)d_in[8];
    const float* b2   = (const float*)d_in[9];
    const float* W3   = (const float*)d_in[10];
    const float* b3   = (const float*)d_in[11];
    const float* c1w  = (const float*)d_in[12];
    const float* c1b  = (const float*)d_in[13];
    const float* c2w  = (const float*)d_in[14];
    const float* c2b  = (const float*)d_in[15];
    const float* l1w  = (const float*)d_in[16];
    const float* l1b  = (const float*)d_in[17];
    const float* l2w  = (const float*)d_in[18];
    const float* l2b  = (const float*)d_in[19];
    float*       out  = (float*)d_out;

    const int E = in_sizes[1] / 2;   // 1638400
    seal_fused<<<NGR, NTHR, 0, stream>>>(z, ei, ei + E, zemb,
                                         W0, b0, W1, b1, W2, b2, W3, b3,
                                         c1w, c1b, c2w, c2b, l1w, l1b, l2w, l2b,
                                         out);
}